// Round 14
// baseline (159.097 us; speedup 1.0000x reference)
//
#include <hip/hip_runtime.h>

#define C 64
#define NBMAX 1664          // max buckets the LDS arrays support (N <= 106496)
#define CAP 1024            // fixed bucket capacity: mean 800 + 7.9 sigma
#define SCAT_BLOCKS 256

static __device__ __forceinline__ unsigned short f2bf(float f) {
    unsigned u = __float_as_uint(f);
    u += 0x7FFFu + ((u >> 16) & 1u);         // round-to-nearest-even
    return (unsigned short)(u >> 16);
}
static __device__ __forceinline__ float bf2f(unsigned short h) {
    return __uint_as_float((unsigned)h << 16);
}

// ======= xw half-row: lane computes 32 channels of y[r] = bf16(x[r] @ W).
//         half is wave-uniform -> W reads scalarize to s_load broadcast.
//         acc[32] fits in VGPRs: no scratch spill (the R13 lesson). =======
static __device__ __forceinline__ void xw_half(const float* __restrict__ x,
                                               const float* __restrict__ W,
                                               unsigned short* __restrict__ yb,
                                               int wvbase, int half, int lane, int n) {
    int r = wvbase + lane;
    int rc = r < n ? r : n - 1;              // clamp: keep control flow uniform
    const float4* xr = reinterpret_cast<const float4*>(x + (size_t)rc * C);
    const int j0 = half * 32;
    float acc[32];
#pragma unroll
    for (int j = 0; j < 32; ++j) acc[j] = 0.0f;
#pragma unroll 4
    for (int k4 = 0; k4 < 16; ++k4) {
        float4 xv = xr[k4];
        const float* w0 = &W[(k4 * 4 + 0) * C + j0];
        const float* w1 = &W[(k4 * 4 + 1) * C + j0];
        const float* w2 = &W[(k4 * 4 + 2) * C + j0];
        const float* w3 = &W[(k4 * 4 + 3) * C + j0];
#pragma unroll
        for (int j = 0; j < 32; ++j) {
            acc[j] += xv.x * w0[j];
            acc[j] += xv.y * w1[j];
            acc[j] += xv.z * w2[j];
            acc[j] += xv.w * w3[j];
        }
    }
    if (r < n) {
        uint4* yr = reinterpret_cast<uint4*>(yb + (size_t)r * C + j0);
#pragma unroll
        for (int q = 0; q < 4; ++q) {
            uint4 v;
            v.x = (unsigned)f2bf(acc[8 * q + 0]) | ((unsigned)f2bf(acc[8 * q + 1]) << 16);
            v.y = (unsigned)f2bf(acc[8 * q + 2]) | ((unsigned)f2bf(acc[8 * q + 3]) << 16);
            v.z = (unsigned)f2bf(acc[8 * q + 4]) | ((unsigned)f2bf(acc[8 * q + 5]) << 16);
            v.w = (unsigned)f2bf(acc[8 * q + 6]) | ((unsigned)f2bf(acc[8 * q + 7]) << 16);
            yr[q] = v;
        }
    }
}

// ======= 0) init bucket cursors to fixed bases =======
__global__ void k_init(int* __restrict__ gcur, int nb) {
    int i = blockIdx.x * blockDim.x + threadIdx.x;
    if (i < nb) gcur[i] = i * CAP;
}

// ======= 1) scatter edges into fixed-capacity buckets ∥ y = bf16(x@W) =======
// u64 layout: bits[0:6)=row&63, [6:38)=col, [38:53)=ew q15
__global__ __launch_bounds__(256) void k_scatter_xw(const int* __restrict__ row,
                                                    const int* __restrict__ col,
                                                    const float* __restrict__ ew,
                                                    int* __restrict__ gcur,
                                                    unsigned long long* __restrict__ ebuf,
                                                    int e, int nb,
                                                    const float* __restrict__ x,
                                                    const float* __restrict__ W,
                                                    unsigned short* __restrict__ yb,
                                                    int n, int nbXW) {
    __shared__ int h[NBMAX];
    __shared__ int base[NBMAX];
    if ((int)blockIdx.x < nbXW) {
        // 4 waves/block; wave gw handles rows [(gw>>1)*64, +64), channel-half gw&1
        int gw = blockIdx.x * 4 + (threadIdx.x >> 6);
        xw_half(x, W, yb, (gw >> 1) * 64, gw & 1, threadIdx.x & 63, n);
        return;
    }
    int tid = threadIdx.x;
    int nsb = gridDim.x - nbXW;
    int sb  = blockIdx.x - nbXW;
    int chunk = (e + nsb - 1) / nsb;
    int s0 = sb * chunk;
    int s1 = s0 + chunk; if (s1 > e) s1 = e;
    for (int i = tid; i < nb; i += 256) h[i] = 0;
    __syncthreads();
    // local hist (fire-and-forget LDS atomics, 4-deep load batching)
    for (int i = s0 + tid; i < s1; i += 4 * 256) {
        int b[4];
#pragma unroll
        for (int k = 0; k < 4; ++k) {
            int idx = i + k * 256;
            b[k] = (idx < s1) ? (row[idx] >> 6) : -1;
        }
#pragma unroll
        for (int k = 0; k < 4; ++k)
            if (b[k] >= 0) atomicAdd(&h[b[k]], 1);
    }
    __syncthreads();
    // coalesced per-bucket range reservation
    for (int i = tid; i < nb; i += 256) {
        int c = h[i];
        base[i] = c ? atomicAdd(&gcur[i], c) : 0;
    }
    __syncthreads();
    for (int i = tid; i < nb; i += 256) h[i] = 0;
    __syncthreads();
    // main edge loop: 4-deep phase-split {loads | LDS atomics | stores}
    for (int i = s0 + tid; i < s1; i += 4 * 256) {
        int idx[4], r[4], b[4], c[4], p[4];
        float w[4];
#pragma unroll
        for (int k = 0; k < 4; ++k) {
            idx[k] = i + k * 256;
            bool v = idx[k] < s1;
            r[k] = v ? row[idx[k]] : 0;
            c[k] = v ? col[idx[k]] : 0;
            w[k] = v ? ew[idx[k]] : 0.0f;
            b[k] = r[k] >> 6;
        }
#pragma unroll
        for (int k = 0; k < 4; ++k)
            p[k] = (idx[k] < s1) ? (base[b[k]] + atomicAdd(&h[b[k]], 1)) : 0;
#pragma unroll
        for (int k = 0; k < 4; ++k)
            if (idx[k] < s1 && p[k] < (b[k] + 1) * CAP) {   // capacity guard (never hits)
                unsigned q = (unsigned)(w[k] * 32767.0f + 0.5f);
                unsigned long long v = (unsigned long long)(r[k] & 63) |
                                       ((unsigned long long)(unsigned)c[k] << 6) |
                                       ((unsigned long long)q << 38);
                ebuf[p[k]] = v;
            }
    }
}

// ======= 2) per-bucket row grouping in LDS -> rowinfo(start,cnt) + dinv =======
__global__ __launch_bounds__(256) void k_pass2(const unsigned long long* __restrict__ ebuf,
                                               const int* __restrict__ gcur,
                                               uint2* __restrict__ rowinfo,
                                               uint2* __restrict__ edges,
                                               float* __restrict__ dinv, int n) {
    __shared__ int   cnt[64];
    __shared__ float sum[64];
    __shared__ int   rbase[64];
    int b = blockIdx.x;
    int r0 = b << 6;
    int tid = threadIdx.x;
    if (tid < 64) { cnt[tid] = 0; sum[tid] = 0.0f; }
    __syncthreads();
    int s0 = b * CAP;
    int s1 = gcur[b]; if (s1 > s0 + CAP) s1 = s0 + CAP;
    for (int i = s0 + tid; i < s1; i += 256) {
        unsigned long long v = ebuf[i];
        int rl = (int)(v & 63ull);
        float w = (float)((v >> 38) & 0x7FFFull) * (1.0f / 32767.0f);
        atomicAdd(&cnt[rl], 1);
        atomicAdd(&sum[rl], w);
    }
    __syncthreads();
    if (tid < 64) {                          // wave 0: 64-lane shfl scan
        int v = cnt[tid];
        int inc = v;
#pragma unroll
        for (int off = 1; off < 64; off <<= 1) {
            int t = __shfl_up(inc, off);
            if (tid >= off) inc += t;
        }
        int st = s0 + inc - v;
        rbase[tid] = st;
        int r = r0 + tid;
        if (r < n) {
            rowinfo[r] = make_uint2((unsigned)st, (unsigned)v);
            dinv[r] = rsqrtf(1.0f + sum[tid]);
        }
        cnt[tid] = 0;
    }
    __syncthreads();
    for (int i = s0 + tid; i < s1; i += 256) {
        unsigned long long v = ebuf[i];
        int rl = (int)(v & 63ull);
        unsigned cc = (unsigned)((v >> 6) & 0xFFFFFFFFull);
        float w = (float)((v >> 38) & 0x7FFFull) * (1.0f / 32767.0f);
        int p = rbase[rl] + atomicAdd(&cnt[rl], 1);
        edges[p] = make_uint2(cc, __float_as_uint(w));
    }
}

// ======= 3) pull aggregation: one wave per row, 8-deep gather ILP =======
__global__ __launch_bounds__(256) void k_agg(const uint2* __restrict__ rowinfo,
                                             const float* __restrict__ dinv,
                                             const unsigned short* __restrict__ yb,
                                             const uint2* __restrict__ edges,
                                             const float* __restrict__ bias,
                                             float* __restrict__ out, int n) {
    int wid = (blockIdx.x * blockDim.x + threadIdx.x) >> 6;
    int lane = threadIdx.x & 63;
    if (wid >= n) return;
    uint2 ri = rowinfo[wid];
    int start = (int)ri.x;
    int end   = start + (int)ri.y;
    float acc = 0.0f;
    for (int tb = start; tb < end; tb += 64) {
        int m = end - tb;
        if (m > 64) m = 64;
        float w = 0.0f;
        uint2 ed = make_uint2(0u, 0u);
        if (lane < m) {
            ed = edges[tb + lane];
            w = __uint_as_float(ed.y) * dinv[ed.x];   // ew * dinv[col]
        }
        int j = 0;
        for (; j + 8 <= m; j += 8) {
            int cc[8]; float ww[8]; unsigned short aa[8];
#pragma unroll
            for (int q = 0; q < 8; ++q) {
                cc[q] = __shfl((int)ed.x, j + q);
                ww[q] = __shfl(w, j + q);
            }
#pragma unroll
            for (int q = 0; q < 8; ++q) aa[q] = yb[(size_t)cc[q] * C + lane];
#pragma unroll
            for (int q = 0; q < 8; ++q) acc += ww[q] * bf2f(aa[q]);
        }
        for (; j + 4 <= m; j += 4) {
            int cc[4]; float ww[4]; unsigned short aa[4];
#pragma unroll
            for (int q = 0; q < 4; ++q) {
                cc[q] = __shfl((int)ed.x, j + q);
                ww[q] = __shfl(w, j + q);
            }
#pragma unroll
            for (int q = 0; q < 4; ++q) aa[q] = yb[(size_t)cc[q] * C + lane];
#pragma unroll
            for (int q = 0; q < 4; ++q) acc += ww[q] * bf2f(aa[q]);
        }
        for (; j < m; ++j) {
            int cj   = __shfl((int)ed.x, j);
            float wj = __shfl(w, j);
            acc += wj * bf2f(yb[(size_t)cj * C + lane]);
        }
    }
    float d  = dinv[wid];
    float yl = bf2f(yb[(size_t)wid * C + lane]);
    out[(size_t)wid * C + lane] = bias[lane] + d * acc + d * d * yl;
}

extern "C" void kernel_launch(void* const* d_in, const int* in_sizes, int n_in,
                              void* d_out, int out_size, void* d_ws, size_t ws_size,
                              hipStream_t stream) {
    const float* x    = (const float*)d_in[0];
    const int*   ei   = (const int*)d_in[1];
    const float* ew   = (const float*)d_in[2];
    const float* W    = (const float*)d_in[3];
    const float* bias = (const float*)d_in[4];
    float* out = (float*)d_out;

    const int N = in_sizes[0] / C;   // 100000
    const int E = in_sizes[2];       // 1250000
    const int* row = ei;
    const int* col = ei + E;

    const int NP = ((N + 1023) / 1024) * 1024;   // padded
    const int nb = (N + 63) >> 6;                // buckets (1563), <= NBMAX

    // ws layout: dinv[NP] f32 | yb[NP*C] u16 | rowinfo[NP] uint2 | gcur[2048] int
    //            | ebuf[nb*CAP] u64 | edges[nb*CAP] uint2      (~40 MB total)
    char* p = (char*)d_ws;
    float*          dinv     = (float*)p;           p += (size_t)NP * 4;
    unsigned short* yb       = (unsigned short*)p;  p += (size_t)NP * C * 2;
    uint2*          rowinfo  = (uint2*)p;           p += (size_t)NP * 8;
    int*            gcur     = (int*)p;             p += 2048 * 4;
    unsigned long long* ebuf = (unsigned long long*)p; p += (size_t)nb * CAP * 8;
    uint2*          edges    = (uint2*)p;

    // xw: 2 half-row waves per 64 rows -> 2*nb waves, 4 waves/block
    const int nbXW = (2 * nb + 3) / 4;          // 782 blocks
    const int nbRowWave = (N * C + 255) / 256;  // one wave per row (25000)

    k_init<<<(nb + 255) / 256, 256, 0, stream>>>(gcur, nb);
    k_scatter_xw<<<nbXW + SCAT_BLOCKS, 256, 0, stream>>>(row, col, ew, gcur, ebuf, E, nb,
                                                         x, W, yb, N, nbXW);
    k_pass2<<<nb, 256, 0, stream>>>(ebuf, gcur, rowinfo, edges, dinv, N);
    k_agg<<<nbRowWave, 256, 0, stream>>>(rowinfo, dinv, yb, edges, bias, out, N);
}

// Round 15
// 126.728 us; speedup vs baseline: 1.2554x; 1.2554x over previous
//
#include <hip/hip_runtime.h>

#define C 64
#define NBMAX 1664          // max buckets the LDS arrays support (N <= 106496)
#define CAP 1024            // fixed bucket capacity: mean 800 + 7.9 sigma
#define SCAT_BLOCKS 256

static __device__ __forceinline__ unsigned short f2bf(float f) {
    unsigned u = __float_as_uint(f);
    u += 0x7FFFu + ((u >> 16) & 1u);         // round-to-nearest-even
    return (unsigned short)(u >> 16);
}
static __device__ __forceinline__ float bf2f(unsigned short h) {
    return __uint_as_float((unsigned)h << 16);
}

// ======= xw row body (R12-verified config — do not perturb; R13/R14 both regressed) ====
static __device__ __forceinline__ void xw_row(const float* __restrict__ x,
                                              const float* __restrict__ W,
                                              unsigned short* __restrict__ yb,
                                              int r, int n) {
    int rc = r < n ? r : n - 1;              // clamp: keep control flow uniform
    const float4* xr = reinterpret_cast<const float4*>(x + (size_t)rc * C);
    float acc[C];
#pragma unroll
    for (int j = 0; j < C; ++j) acc[j] = 0.0f;
#pragma unroll 4
    for (int k4 = 0; k4 < C / 4; ++k4) {
        float4 xv = xr[k4];
        const float* w0 = &W[(k4 * 4 + 0) * C];
        const float* w1 = &W[(k4 * 4 + 1) * C];
        const float* w2 = &W[(k4 * 4 + 2) * C];
        const float* w3 = &W[(k4 * 4 + 3) * C];
#pragma unroll
        for (int j = 0; j < C; ++j) {
            acc[j] += xv.x * w0[j];
            acc[j] += xv.y * w1[j];
            acc[j] += xv.z * w2[j];
            acc[j] += xv.w * w3[j];
        }
    }
    if (r < n) {
        uint4* yr = reinterpret_cast<uint4*>(yb + (size_t)r * C);
#pragma unroll
        for (int q = 0; q < 8; ++q) {
            uint4 v;
            v.x = (unsigned)f2bf(acc[8 * q + 0]) | ((unsigned)f2bf(acc[8 * q + 1]) << 16);
            v.y = (unsigned)f2bf(acc[8 * q + 2]) | ((unsigned)f2bf(acc[8 * q + 3]) << 16);
            v.z = (unsigned)f2bf(acc[8 * q + 4]) | ((unsigned)f2bf(acc[8 * q + 5]) << 16);
            v.w = (unsigned)f2bf(acc[8 * q + 6]) | ((unsigned)f2bf(acc[8 * q + 7]) << 16);
            yr[q] = v;
        }
    }
}

// ======= 0) init bucket cursors to fixed bases =======
__global__ void k_init(int* __restrict__ gcur, int nb) {
    int i = blockIdx.x * blockDim.x + threadIdx.x;
    if (i < nb) gcur[i] = i * CAP;
}

// ======= 1) scatter edges into fixed-capacity buckets ∥ y = bf16(x@W)  (R12 config) ====
// u64 layout: bits[0:6)=row&63, [6:38)=col, [38:53)=ew q15
__global__ __launch_bounds__(256) void k_scatter_xw(const int* __restrict__ row,
                                                    const int* __restrict__ col,
                                                    const float* __restrict__ ew,
                                                    int* __restrict__ gcur,
                                                    unsigned long long* __restrict__ ebuf,
                                                    int e, int nb,
                                                    const float* __restrict__ x,
                                                    const float* __restrict__ W,
                                                    unsigned short* __restrict__ yb,
                                                    int n, int nbXW) {
    __shared__ int h[NBMAX];
    __shared__ int base[NBMAX];
    if ((int)blockIdx.x < nbXW) {
        xw_row(x, W, yb, blockIdx.x * blockDim.x + threadIdx.x, n);
        return;
    }
    int tid = threadIdx.x;
    int nsb = gridDim.x - nbXW;
    int sb  = blockIdx.x - nbXW;
    int chunk = (e + nsb - 1) / nsb;
    int s0 = sb * chunk;
    int s1 = s0 + chunk; if (s1 > e) s1 = e;
    for (int i = tid; i < nb; i += 256) h[i] = 0;
    __syncthreads();
    for (int i = s0 + tid; i < s1; i += 4 * 256) {
        int b[4];
#pragma unroll
        for (int k = 0; k < 4; ++k) {
            int idx = i + k * 256;
            b[k] = (idx < s1) ? (row[idx] >> 6) : -1;
        }
#pragma unroll
        for (int k = 0; k < 4; ++k)
            if (b[k] >= 0) atomicAdd(&h[b[k]], 1);
    }
    __syncthreads();
    for (int i = tid; i < nb; i += 256) {
        int c = h[i];
        base[i] = c ? atomicAdd(&gcur[i], c) : 0;   // coalesced returning atomics
    }
    __syncthreads();
    for (int i = tid; i < nb; i += 256) h[i] = 0;
    __syncthreads();
    for (int i = s0 + tid; i < s1; i += 4 * 256) {
        int idx[4], r[4], b[4], c[4], p[4];
        float w[4];
#pragma unroll
        for (int k = 0; k < 4; ++k) {
            idx[k] = i + k * 256;
            bool v = idx[k] < s1;
            r[k] = v ? row[idx[k]] : 0;
            c[k] = v ? col[idx[k]] : 0;
            w[k] = v ? ew[idx[k]] : 0.0f;
            b[k] = r[k] >> 6;
        }
#pragma unroll
        for (int k = 0; k < 4; ++k)
            p[k] = (idx[k] < s1) ? (base[b[k]] + atomicAdd(&h[b[k]], 1)) : 0;
#pragma unroll
        for (int k = 0; k < 4; ++k)
            if (idx[k] < s1 && p[k] < (b[k] + 1) * CAP) {   // capacity guard (never hits)
                unsigned q = (unsigned)(w[k] * 32767.0f + 0.5f);
                unsigned long long v = (unsigned long long)(r[k] & 63) |
                                       ((unsigned long long)(unsigned)c[k] << 6) |
                                       ((unsigned long long)q << 38);
                ebuf[p[k]] = v;
            }
    }
}

// ======= 2) per-bucket row grouping in LDS -> rowinfo(start,cnt) + dinv =======
__global__ __launch_bounds__(256) void k_pass2(const unsigned long long* __restrict__ ebuf,
                                               const int* __restrict__ gcur,
                                               uint2* __restrict__ rowinfo,
                                               uint2* __restrict__ edges,
                                               float* __restrict__ dinv, int n) {
    __shared__ int   cnt[64];
    __shared__ float sum[64];
    __shared__ int   rbase[64];
    int b = blockIdx.x;
    int r0 = b << 6;
    int tid = threadIdx.x;
    if (tid < 64) { cnt[tid] = 0; sum[tid] = 0.0f; }
    __syncthreads();
    int s0 = b * CAP;
    int s1 = gcur[b]; if (s1 > s0 + CAP) s1 = s0 + CAP;
    for (int i = s0 + tid; i < s1; i += 256) {
        unsigned long long v = ebuf[i];
        int rl = (int)(v & 63ull);
        float w = (float)((v >> 38) & 0x7FFFull) * (1.0f / 32767.0f);
        atomicAdd(&cnt[rl], 1);
        atomicAdd(&sum[rl], w);
    }
    __syncthreads();
    if (tid < 64) {                          // wave 0: 64-lane shfl scan
        int v = cnt[tid];
        int inc = v;
#pragma unroll
        for (int off = 1; off < 64; off <<= 1) {
            int t = __shfl_up(inc, off);
            if (tid >= off) inc += t;
        }
        int st = s0 + inc - v;
        rbase[tid] = st;
        int r = r0 + tid;
        if (r < n) {
            rowinfo[r] = make_uint2((unsigned)st, (unsigned)v);
            dinv[r] = rsqrtf(1.0f + sum[tid]);
        }
        cnt[tid] = 0;
    }
    __syncthreads();
    for (int i = s0 + tid; i < s1; i += 256) {
        unsigned long long v = ebuf[i];
        int rl = (int)(v & 63ull);
        unsigned cc = (unsigned)((v >> 6) & 0xFFFFFFFFull);
        float w = (float)((v >> 38) & 0x7FFFull) * (1.0f / 32767.0f);
        int p = rbase[rl] + atomicAdd(&cnt[rl], 1);
        edges[p] = make_uint2(cc, __float_as_uint(w));
    }
}

// ======= 3) pull aggregation: 2 edges/iteration.
//         lane = channel-PAIR (uint gather = 4 B); half-wave 0 -> edge j, half 1 -> j+1.
//         Per edge-pair: 2 shfl + 1 load/lane (vs 4 shfl + 2 loads before). =======
__global__ __launch_bounds__(256) void k_agg(const uint2* __restrict__ rowinfo,
                                             const float* __restrict__ dinv,
                                             const unsigned short* __restrict__ yb,
                                             const uint2* __restrict__ edges,
                                             const float* __restrict__ bias,
                                             float* __restrict__ out, int n) {
    int wid = (blockIdx.x * blockDim.x + threadIdx.x) >> 6;
    int lane = threadIdx.x & 63;
    if (wid >= n) return;
    uint2 ri = rowinfo[wid];
    int start = (int)ri.x;
    int m_all = (int)ri.y;
    int half = lane >> 5;
    int ch2 = (lane & 31) * 2;               // this lane's channel pair
    float acc0 = 0.0f, acc1 = 0.0f;
    for (int tb = 0; tb < m_all; tb += 64) {
        int m = m_all - tb;
        if (m > 64) m = 64;
        uint2 ed = make_uint2(0u, 0u);
        float w = 0.0f;
        if (lane < m) {
            ed = edges[start + tb + lane];
            w = __uint_as_float(ed.y) * dinv[ed.x];   // ew * dinv[col]
        }
        int me = m & ~1;
        int j = 0;
        for (; j + 8 <= me; j += 8) {        // 4 pairs = 8 edges, 4 gathers in flight
            int cc[4]; float ww[4]; unsigned uu[4];
#pragma unroll
            for (int q = 0; q < 4; ++q) {
                int src = j + 2 * q + half;
                cc[q] = __shfl((int)ed.x, src);
                ww[q] = __shfl(w, src);
            }
#pragma unroll
            for (int q = 0; q < 4; ++q)
                uu[q] = *reinterpret_cast<const unsigned*>(&yb[(size_t)cc[q] * C + ch2]);
#pragma unroll
            for (int q = 0; q < 4; ++q) {
                acc0 += ww[q] * bf2f((unsigned short)(uu[q] & 0xFFFFu));
                acc1 += ww[q] * bf2f((unsigned short)(uu[q] >> 16));
            }
        }
        for (; j + 2 <= me; j += 2) {
            int src = j + half;
            int cj   = __shfl((int)ed.x, src);
            float wj = __shfl(w, src);
            unsigned u = *reinterpret_cast<const unsigned*>(&yb[(size_t)cj * C + ch2]);
            acc0 += wj * bf2f((unsigned short)(u & 0xFFFFu));
            acc1 += wj * bf2f((unsigned short)(u >> 16));
        }
        if (j < m) {                          // odd tail: half 0 only
            int cj   = __shfl((int)ed.x, j);
            float wj = __shfl(w, j);
            if (half == 0) {
                unsigned u = *reinterpret_cast<const unsigned*>(&yb[(size_t)cj * C + ch2]);
                acc0 += wj * bf2f((unsigned short)(u & 0xFFFFu));
                acc1 += wj * bf2f((unsigned short)(u >> 16));
            }
        }
    }
    acc0 += __shfl_xor(acc0, 32);            // combine even/odd edge halves
    acc1 += __shfl_xor(acc1, 32);
    if (half == 0) {
        float d = dinv[wid];
        unsigned su = *reinterpret_cast<const unsigned*>(&yb[(size_t)wid * C + ch2]);
        float2 b2 = *reinterpret_cast<const float2*>(&bias[ch2]);
        float2 o;
        o.x = b2.x + d * acc0 + d * d * bf2f((unsigned short)(su & 0xFFFFu));
        o.y = b2.y + d * acc1 + d * d * bf2f((unsigned short)(su >> 16));
        *reinterpret_cast<float2*>(&out[(size_t)wid * C + ch2]) = o;
    }
}

extern "C" void kernel_launch(void* const* d_in, const int* in_sizes, int n_in,
                              void* d_out, int out_size, void* d_ws, size_t ws_size,
                              hipStream_t stream) {
    const float* x    = (const float*)d_in[0];
    const int*   ei   = (const int*)d_in[1];
    const float* ew   = (const float*)d_in[2];
    const float* W    = (const float*)d_in[3];
    const float* bias = (const float*)d_in[4];
    float* out = (float*)d_out;

    const int N = in_sizes[0] / C;   // 100000
    const int E = in_sizes[2];       // 1250000
    const int* row = ei;
    const int* col = ei + E;

    const int NP = ((N + 1023) / 1024) * 1024;   // padded
    const int nb = (N + 63) >> 6;                // buckets (1563), <= NBMAX

    // ws layout: dinv[NP] f32 | yb[NP*C] u16 | rowinfo[NP] uint2 | gcur[2048] int
    //            | ebuf[nb*CAP] u64 | edges[nb*CAP] uint2      (~40 MB total)
    char* p = (char*)d_ws;
    float*          dinv     = (float*)p;           p += (size_t)NP * 4;
    unsigned short* yb       = (unsigned short*)p;  p += (size_t)NP * C * 2;
    uint2*          rowinfo  = (uint2*)p;           p += (size_t)NP * 8;
    int*            gcur     = (int*)p;             p += 2048 * 4;
    unsigned long long* ebuf = (unsigned long long*)p; p += (size_t)nb * CAP * 8;
    uint2*          edges    = (uint2*)p;

    const int nbXW = (N + 255) / 256;           // xw blocks (391) — R12 config
    const int nbRowWave = (N * C + 255) / 256;  // one wave per row (25000)

    k_init<<<(nb + 255) / 256, 256, 0, stream>>>(gcur, nb);
    k_scatter_xw<<<nbXW + SCAT_BLOCKS, 256, 0, stream>>>(row, col, ew, gcur, ebuf, E, nb,
                                                         x, W, yb, N, nbXW);
    k_pass2<<<nb, 256, 0, stream>>>(ebuf, gcur, rowinfo, edges, dinv, N);
    k_agg<<<nbRowWave, 256, 0, stream>>>(rowinfo, dinv, yb, edges, bias, out, N);
}